// Round 3
// baseline (42944.360 us; speedup 1.0000x reference)
//
#include <hip/hip_runtime.h>
#include <hip/hip_bf16.h>

#define BB 128
#define SS 1000
#define II 128
#define HH 1024
#define G4 4096
#define KK (II + HH)   // 1152
#define NC 50
#define NB 256         // persistent blocks
#define SPIN_LIM (1 << 20)

typedef __attribute__((ext_vector_type(8))) short short8v;
typedef __attribute__((ext_vector_type(4))) float f32x4;

static __device__ __forceinline__ short f2bf(float f) {
    union { float f; unsigned u; } v; v.f = f;
    unsigned u = v.u;
    u += 0x7FFFu + ((u >> 16) & 1u);   // RNE
    return (short)(u >> 16);
}

// ---------------------------------------------------------------------------
// Weight prep: Bt[n][k] (bf16, n = gate*1024 + j, k in [0,1152)) from fp32.
// grid (36, 32, 4), block (32, 8)
// ---------------------------------------------------------------------------
__global__ void prep_weights(const float* __restrict__ Wx0, const float* __restrict__ Wx1,
                             const float* __restrict__ Wx2, const float* __restrict__ Wx3,
                             const float* __restrict__ Wh0, const float* __restrict__ Wh1,
                             const float* __restrict__ Wh2, const float* __restrict__ Wh3,
                             short* __restrict__ Bt) {
    __shared__ float lds[32][33];
    const int kt = blockIdx.x, jt = blockIdx.y, g = blockIdx.z;
    const int tx = threadIdx.x, ty = threadIdx.y;
    const float* Wx = (g == 0) ? Wx0 : (g == 1) ? Wx1 : (g == 2) ? Wx2 : Wx3;
    const float* Wh = (g == 0) ? Wh0 : (g == 1) ? Wh1 : (g == 2) ? Wh2 : Wh3;
    const int k0 = kt * 32, j0 = jt * 32;
#pragma unroll
    for (int r = 0; r < 4; r++) {
        int kk = k0 + ty + r * 8;
        float v = (kk < II) ? Wx[kk * HH + j0 + tx] : Wh[(kk - II) * HH + j0 + tx];
        lds[ty + r * 8][tx] = v;
    }
    __syncthreads();
#pragma unroll
    for (int r = 0; r < 4; r++) {
        int jj = ty + r * 8;
        Bt[(size_t)(g * HH + j0 + jj) * KK + k0 + tx] = f2bf(lds[tx][jj]);
    }
}

// ---------------------------------------------------------------------------
// Pack bias [4096], zero hbuf[0], zero barrier flags. grid 512, block 256.
// ---------------------------------------------------------------------------
__global__ void prep_misc(const float* __restrict__ bi, const float* __restrict__ bf_,
                          const float* __restrict__ bg, const float* __restrict__ bo,
                          float* __restrict__ b4, short* __restrict__ hbuf,
                          unsigned* __restrict__ flags) {
    int i = blockIdx.x * 256 + threadIdx.x;
    if (i < G4) {
        float v = (i < HH) ? bi[i] : (i < 2 * HH) ? bf_[i - HH]
                : (i < 3 * HH) ? bg[i - 2 * HH] : bo[i - 3 * HH];
        b4[i] = v;
    }
    if (i < BB * HH) hbuf[i] = 0;   // h(0) = 0 in buffer 0
    if (i < 1024) flags[i] = 0;     // barrier flags + go
}

// ---------------------------------------------------------------------------
// Persistent LSTM, plain launch, custom grid barrier.
// 256 blocks x 256 threads, __launch_bounds__(256,1) -> >=1 block/CU, grid ==
// CU count -> all co-resident (sanctioned k x 256 pattern).
// Block: mg=bid&7 (16 batch rows), jg=bid>>3 (32 cols). Wave g = gate g,
// B-slice in 288 VGPRs. c in LDS. h stores = device-scope atomic u32 (IF$),
// flag barrier (release/acquire agent) + __threadfence() (L2 inv) per step.
// ---------------------------------------------------------------------------
__global__ __launch_bounds__(256, 1) void lstm_persist(
    const float* __restrict__ x, const short* __restrict__ Bt,
    const float* __restrict__ b4, short* __restrict__ hbuf,
    float* __restrict__ hf, unsigned* __restrict__ flags) {
    const int bid = blockIdx.x;
    const int mg = bid & 7, jg = bid >> 3;
    const int m0 = mg * 16, j0 = jg * 32;
    const int tid = threadIdx.x;
    const int g = tid >> 6, l = tid & 63;
    const int lq = l >> 4, lr = l & 15;
    unsigned* go = flags + 512;

    __shared__ float g4s[4][16][33];
    __shared__ float c_lds[16][33];
    __shared__ int dead;

    if (tid == 0) dead = 0;
    for (int i = tid; i < 16 * 33; i += 256) ((float*)c_lds)[i] = 0.f;

    // --- this wave's weight slice -> 288 VGPRs (once) ---
    short8v Bw[36][2];
    {
        const short* Bg = Bt + (size_t)(g * HH + j0) * KK;
#pragma unroll
        for (int kk = 0; kk < 36; kk++) {
#pragma unroll
            for (int nt = 0; nt < 2; nt++) {
                Bw[kk][nt] = *(const short8v*)(Bg + (size_t)(nt * 16 + lr) * KK + kk * 32 + lq * 8);
            }
        }
    }

    const int arow = m0 + lr;                       // A-operand batch row
    const float* xrow = x + (size_t)arow * SS * II;

    // elementwise constants: thread -> (m_e, cols j2, j2+1)
    const int m_e = tid >> 4;            // 0..15
    const int j2 = (tid & 15) * 2;       // 0..30
    const float bi0 = b4[j0 + j2],          bi1 = b4[j0 + j2 + 1];
    const float bf0 = b4[HH + j0 + j2],     bf1 = b4[HH + j0 + j2 + 1];
    const float bg0 = b4[2 * HH + j0 + j2], bg1 = b4[2 * HH + j0 + j2 + 1];
    const float bo0 = b4[3 * HH + j0 + j2], bo1 = b4[3 * HH + j0 + j2 + 1];

    __syncthreads();

    for (int t = 0; t < SS; t++) {
        const short* hcur = hbuf + (size_t)(t & 1) * (BB * HH);
        short* hnxt = hbuf + (size_t)((t + 1) & 1) * (BB * HH);

        f32x4 acc0 = {0.f, 0.f, 0.f, 0.f}, acc1 = acc0;

        // k-tiles 0..3: x (fp32 -> bf16 on the fly)
        const float* xt = xrow + (size_t)t * II;
#pragma unroll
        for (int kk = 0; kk < 4; kk++) {
            const float4* xp = (const float4*)(xt + kk * 32 + lq * 8);
            float4 x0 = xp[0], x1 = xp[1];
            short8v a;
            a[0] = f2bf(x0.x); a[1] = f2bf(x0.y); a[2] = f2bf(x0.z); a[3] = f2bf(x0.w);
            a[4] = f2bf(x1.x); a[5] = f2bf(x1.y); a[6] = f2bf(x1.z); a[7] = f2bf(x1.w);
            acc0 = __builtin_amdgcn_mfma_f32_16x16x32_bf16(a, Bw[kk][0], acc0, 0, 0, 0);
            acc1 = __builtin_amdgcn_mfma_f32_16x16x32_bf16(a, Bw[kk][1], acc1, 0, 0, 0);
        }
        // k-tiles 4..35: h
        const short8v* hrow = (const short8v*)(hcur + (size_t)arow * HH);
#pragma unroll
        for (int kk = 4; kk < 36; kk++) {
            short8v a = hrow[(kk - 4) * 4 + lq];
            acc0 = __builtin_amdgcn_mfma_f32_16x16x32_bf16(a, Bw[kk][0], acc0, 0, 0, 0);
            acc1 = __builtin_amdgcn_mfma_f32_16x16x32_bf16(a, Bw[kk][1], acc1, 0, 0, 0);
        }

        // gates -> LDS   (C/D map: col = lane&15, row = lq*4 + r)
#pragma unroll
        for (int r = 0; r < 4; r++) {
            g4s[g][lq * 4 + r][lr] = acc0[r];
            g4s[g][lq * 4 + r][16 + lr] = acc1[r];
        }
        __syncthreads();

        // elementwise: 1 thread -> (m_e, j2) and (m_e, j2+1)
        {
            float gi0 = g4s[0][m_e][j2] + bi0, gi1 = g4s[0][m_e][j2 + 1] + bi1;
            float gf0 = g4s[1][m_e][j2] + bf0, gf1 = g4s[1][m_e][j2 + 1] + bf1;
            float gg0 = g4s[2][m_e][j2] + bg0, gg1 = g4s[2][m_e][j2 + 1] + bg1;
            float go0 = g4s[3][m_e][j2] + bo0, go1 = g4s[3][m_e][j2 + 1] + bo1;
            float si0 = 1.f / (1.f + __expf(-gi0)), si1 = 1.f / (1.f + __expf(-gi1));
            float sf0 = 1.f / (1.f + __expf(-gf0)), sf1 = 1.f / (1.f + __expf(-gf1));
            float tg0 = 1.f - 2.f / (__expf(2.f * gg0) + 1.f);
            float tg1 = 1.f - 2.f / (__expf(2.f * gg1) + 1.f);
            float so0 = 1.f / (1.f + __expf(-go0)), so1 = 1.f / (1.f + __expf(-go1));
            float cn0 = sf0 * c_lds[m_e][j2] + si0 * tg0;
            float cn1 = sf1 * c_lds[m_e][j2 + 1] + si1 * tg1;
            c_lds[m_e][j2] = cn0;
            c_lds[m_e][j2 + 1] = cn1;
            float h0 = so0 * (1.f - 2.f / (__expf(2.f * cn0) + 1.f));
            float h1 = so1 * (1.f - 2.f / (__expf(2.f * cn1) + 1.f));
            unsigned pv = (unsigned)(unsigned short)f2bf(h0)
                        | ((unsigned)(unsigned short)f2bf(h1) << 16);
            unsigned* hp = (unsigned*)(hnxt + (size_t)(m0 + m_e) * HH + j0 + j2);
            __hip_atomic_store(hp, pv, __ATOMIC_RELAXED, __HIP_MEMORY_SCOPE_AGENT);
            if (t == SS - 1) {
                float2 hv = make_float2(h0, h1);
                *(float2*)(hf + (size_t)(m0 + m_e) * HH + j0 + j2) = hv;
            }
        }

        // ---- grid barrier, epoch e = t+1 ----
        const unsigned e = (unsigned)(t + 1);
        __syncthreads();   // drains vmcnt -> all h atomic-stores globally visible
        if (!dead) {
            if (tid == 0)
                __hip_atomic_store(&flags[bid], e, __ATOMIC_RELEASE, __HIP_MEMORY_SCOPE_AGENT);
            if (bid == 0) {
                if (tid < 64) {
                    for (int f = tid; f < NB; f += 64) {
                        int it = 0;
                        while (__hip_atomic_load(&flags[f], __ATOMIC_RELAXED,
                                                 __HIP_MEMORY_SCOPE_AGENT) < e) {
                            if (++it > SPIN_LIM) { dead = 1; break; }
                        }
                        if (dead) break;
                    }
                }
                __syncthreads();
                if (tid == 0)
                    __hip_atomic_store(go, e, __ATOMIC_RELEASE, __HIP_MEMORY_SCOPE_AGENT);
            } else {
                if (tid == 0) {
                    int it = 0;
                    while (__hip_atomic_load(go, __ATOMIC_ACQUIRE,
                                             __HIP_MEMORY_SCOPE_AGENT) < e) {
                        if (++it > SPIN_LIM) { dead = 1; break; }
                    }
                }
                __syncthreads();
            }
            __threadfence();   // acquire side: invalidate L1/L2 for fresh h reads
        }
    }
}

// ---------------------------------------------------------------------------
// out[b][o] = h[b] . W_out[o] + b_out[o].  grid 128 (b), block 256.
// ---------------------------------------------------------------------------
__global__ void final_linear(const float* __restrict__ hf, const float* __restrict__ Wout,
                             const float* __restrict__ bout, float* __restrict__ out) {
    __shared__ float hs[HH];
    const int b = blockIdx.x;
    for (int i = threadIdx.x; i < HH; i += 256) hs[i] = hf[(size_t)b * HH + i];
    __syncthreads();
    const int w = threadIdx.x >> 6, l = threadIdx.x & 63;
    for (int o = w; o < NC; o += 4) {
        float s = 0.f;
        const float* wr = Wout + (size_t)o * HH;
        for (int jj = l; jj < HH; jj += 64) s += hs[jj] * wr[jj];
#pragma unroll
        for (int d = 32; d > 0; d >>= 1) s += __shfl_down(s, d);
        if (l == 0) out[b * NC + o] = s + bout[o];
    }
}

extern "C" void kernel_launch(void* const* d_in, const int* in_sizes, int n_in,
                              void* d_out, int out_size, void* d_ws, size_t ws_size,
                              hipStream_t stream) {
    const float* x    = (const float*)d_in[0];
    const float* W_ii = (const float*)d_in[1];
    const float* W_hi = (const float*)d_in[2];
    const float* b_ii = (const float*)d_in[3];
    const float* W_if = (const float*)d_in[4];
    const float* W_hf = (const float*)d_in[5];
    const float* b_if = (const float*)d_in[6];
    const float* W_ig = (const float*)d_in[7];
    const float* W_hg = (const float*)d_in[8];
    const float* b_ig = (const float*)d_in[9];
    const float* W_io = (const float*)d_in[10];
    const float* W_ho = (const float*)d_in[11];
    const float* b_io = (const float*)d_in[12];
    const float* W_out = (const float*)d_in[13];
    const float* b_out = (const float*)d_in[14];

    char* ws = (char*)d_ws;
    short* Bt   = (short*)ws;                                  // 9,437,184 B
    float* b4   = (float*)(ws + 9437184);                      // 16,384 B
    short* hbuf = (short*)(ws + 9437184 + 16384);              // 524,288 B
    float* hf   = (float*)(ws + 9437184 + 16384 + 524288);     // 524,288 B
    unsigned* flags = (unsigned*)(ws + 9437184 + 16384 + 524288 + 524288); // 4,096 B

    prep_weights<<<dim3(36, 32, 4), dim3(32, 8), 0, stream>>>(
        W_ii, W_if, W_ig, W_io, W_hi, W_hf, W_hg, W_ho, Bt);
    prep_misc<<<512, 256, 0, stream>>>(b_ii, b_if, b_ig, b_io, b4, hbuf, flags);

    lstm_persist<<<NB, 256, 0, stream>>>(x, Bt, b4, hbuf, hf, flags);

    final_linear<<<BB, 256, 0, stream>>>(hf, W_out, b_out, (float*)d_out);
}

// Round 4
// 19390.903 us; speedup vs baseline: 2.2147x; 2.2147x over previous
//
#include <hip/hip_runtime.h>
#include <hip/hip_bf16.h>

#define BB 128
#define SS 1000
#define II 128
#define HH 1024
#define G4 4096
#define KK (II + HH)   // 1152
#define NC 50
#define NB 256         // persistent blocks
#define SPIN_LIM (1 << 20)

typedef __attribute__((ext_vector_type(8))) short short8v;
typedef __attribute__((ext_vector_type(4))) float f32x4;

static __device__ __forceinline__ short f2bf(float f) {
    union { float f; unsigned u; } v; v.f = f;
    unsigned u = v.u;
    u += 0x7FFFu + ((u >> 16) & 1u);   // RNE
    return (short)(u >> 16);
}

// ---------------------------------------------------------------------------
// Weight prep: Bt[n][k] (bf16, n = gate*1024 + j, k in [0,1152)) from fp32.
// grid (36, 32, 4), block (32, 8)
// ---------------------------------------------------------------------------
__global__ void prep_weights(const float* __restrict__ Wx0, const float* __restrict__ Wx1,
                             const float* __restrict__ Wx2, const float* __restrict__ Wx3,
                             const float* __restrict__ Wh0, const float* __restrict__ Wh1,
                             const float* __restrict__ Wh2, const float* __restrict__ Wh3,
                             short* __restrict__ Bt) {
    __shared__ float lds[32][33];
    const int kt = blockIdx.x, jt = blockIdx.y, g = blockIdx.z;
    const int tx = threadIdx.x, ty = threadIdx.y;
    const float* Wx = (g == 0) ? Wx0 : (g == 1) ? Wx1 : (g == 2) ? Wx2 : Wx3;
    const float* Wh = (g == 0) ? Wh0 : (g == 1) ? Wh1 : (g == 2) ? Wh2 : Wh3;
    const int k0 = kt * 32, j0 = jt * 32;
#pragma unroll
    for (int r = 0; r < 4; r++) {
        int kk = k0 + ty + r * 8;
        float v = (kk < II) ? Wx[kk * HH + j0 + tx] : Wh[(kk - II) * HH + j0 + tx];
        lds[ty + r * 8][tx] = v;
    }
    __syncthreads();
#pragma unroll
    for (int r = 0; r < 4; r++) {
        int jj = ty + r * 8;
        Bt[(size_t)(g * HH + j0 + jj) * KK + k0 + tx] = f2bf(lds[tx][jj]);
    }
}

// ---------------------------------------------------------------------------
// Pack bias [4096], zero hbuf[0], zero barrier flags. grid 512, block 256.
// ---------------------------------------------------------------------------
__global__ void prep_misc(const float* __restrict__ bi, const float* __restrict__ bf_,
                          const float* __restrict__ bg, const float* __restrict__ bo,
                          float* __restrict__ b4, short* __restrict__ hbuf,
                          unsigned* __restrict__ flags) {
    int i = blockIdx.x * 256 + threadIdx.x;
    if (i < G4) {
        float v = (i < HH) ? bi[i] : (i < 2 * HH) ? bf_[i - HH]
                : (i < 3 * HH) ? bg[i - 2 * HH] : bo[i - 3 * HH];
        b4[i] = v;
    }
    if (i < BB * HH) hbuf[i] = 0;   // h(0) = 0 in buffer 0
    if (i < 1024) flags[i] = 0;     // barrier flags
}

// ---------------------------------------------------------------------------
// Persistent LSTM, plain launch, relaxed flag barrier (one acquire-fence/step).
// 256 blocks x 256 threads, __launch_bounds__(256,1): 1 block/CU, co-resident.
// Block: mg=bid&7 (16 batch rows), jg=bid>>3 (32 cols). Wave g = gate g,
// B-slice in registers. c in LDS. h stores = relaxed agent atomic u32 (IF$).
// Barrier: release arrival flag; x-part of t+1 issued under flag propagation;
// all blocks poll all 256 flags RELAXED; one agent acquire fence per step.
// ---------------------------------------------------------------------------
__global__ __launch_bounds__(256, 1) void lstm_persist(
    const float* __restrict__ x, const short* __restrict__ Bt,
    const float* __restrict__ b4, short* __restrict__ hbuf,
    float* __restrict__ hf, unsigned* __restrict__ flags) {
    const int bid = blockIdx.x;
    const int mg = bid & 7, jg = bid >> 3;
    const int m0 = mg * 16, j0 = jg * 32;
    const int tid = threadIdx.x;
    const int g = tid >> 6, l = tid & 63;
    const int lq = l >> 4, lr = l & 15;

    __shared__ float g4s[4][16][33];
    __shared__ float c_lds[16][33];
    __shared__ int dead;

    if (tid == 0) dead = 0;
    for (int i = tid; i < 16 * 33; i += 256) ((float*)c_lds)[i] = 0.f;

    // --- this wave's weight slice -> registers (once) ---
    short8v Bw[36][2];
    {
        const short* Bg = Bt + (size_t)(g * HH + j0) * KK;
#pragma unroll
        for (int kk = 0; kk < 36; kk++) {
#pragma unroll
            for (int nt = 0; nt < 2; nt++) {
                Bw[kk][nt] = *(const short8v*)(Bg + (size_t)(nt * 16 + lr) * KK + kk * 32 + lq * 8);
            }
        }
    }

    const int arow = m0 + lr;                       // A-operand batch row
    const float* xrow = x + (size_t)arow * SS * II;

    // elementwise constants: thread -> (m_e, cols j2, j2+1)
    const int m_e = tid >> 4;            // 0..15
    const int j2 = (tid & 15) * 2;       // 0..30
    const float bi0 = b4[j0 + j2],          bi1 = b4[j0 + j2 + 1];
    const float bf0 = b4[HH + j0 + j2],     bf1 = b4[HH + j0 + j2 + 1];
    const float bg0 = b4[2 * HH + j0 + j2], bg1 = b4[2 * HH + j0 + j2 + 1];
    const float bo0 = b4[3 * HH + j0 + j2], bo1 = b4[3 * HH + j0 + j2 + 1];

    __syncthreads();

    f32x4 acc0 = {0.f, 0.f, 0.f, 0.f}, acc1 = acc0;

    // prologue: x-part of step 0
#pragma unroll
    for (int kk = 0; kk < 4; kk++) {
        const float4* xp = (const float4*)(xrow + kk * 32 + lq * 8);
        float4 x0 = xp[0], x1 = xp[1];
        short8v a;
        a[0] = f2bf(x0.x); a[1] = f2bf(x0.y); a[2] = f2bf(x0.z); a[3] = f2bf(x0.w);
        a[4] = f2bf(x1.x); a[5] = f2bf(x1.y); a[6] = f2bf(x1.z); a[7] = f2bf(x1.w);
        acc0 = __builtin_amdgcn_mfma_f32_16x16x32_bf16(a, Bw[kk][0], acc0, 0, 0, 0);
        acc1 = __builtin_amdgcn_mfma_f32_16x16x32_bf16(a, Bw[kk][1], acc1, 0, 0, 0);
    }

    for (int t = 0; t < SS; t++) {
        const short* hcur = hbuf + (size_t)(t & 1) * (BB * HH);
        short* hnxt = hbuf + (size_t)((t + 1) & 1) * (BB * HH);

        // h-part: k-tiles 4..35
        const short8v* hrow = (const short8v*)(hcur + (size_t)arow * HH);
#pragma unroll
        for (int kk = 4; kk < 36; kk++) {
            short8v a = hrow[(kk - 4) * 4 + lq];
            acc0 = __builtin_amdgcn_mfma_f32_16x16x32_bf16(a, Bw[kk][0], acc0, 0, 0, 0);
            acc1 = __builtin_amdgcn_mfma_f32_16x16x32_bf16(a, Bw[kk][1], acc1, 0, 0, 0);
        }

        // gates -> LDS   (C/D map: col = lane&15, row = lq*4 + r)
#pragma unroll
        for (int r = 0; r < 4; r++) {
            g4s[g][lq * 4 + r][lr] = acc0[r];
            g4s[g][lq * 4 + r][16 + lr] = acc1[r];
        }
        __syncthreads();

        // elementwise: 1 thread -> (m_e, j2) and (m_e, j2+1)
        {
            float gi0 = g4s[0][m_e][j2] + bi0, gi1 = g4s[0][m_e][j2 + 1] + bi1;
            float gf0 = g4s[1][m_e][j2] + bf0, gf1 = g4s[1][m_e][j2 + 1] + bf1;
            float gg0 = g4s[2][m_e][j2] + bg0, gg1 = g4s[2][m_e][j2 + 1] + bg1;
            float go0 = g4s[3][m_e][j2] + bo0, go1 = g4s[3][m_e][j2 + 1] + bo1;
            float si0 = 1.f / (1.f + __expf(-gi0)), si1 = 1.f / (1.f + __expf(-gi1));
            float sf0 = 1.f / (1.f + __expf(-gf0)), sf1 = 1.f / (1.f + __expf(-gf1));
            float tg0 = 1.f - 2.f / (__expf(2.f * gg0) + 1.f);
            float tg1 = 1.f - 2.f / (__expf(2.f * gg1) + 1.f);
            float so0 = 1.f / (1.f + __expf(-go0)), so1 = 1.f / (1.f + __expf(-go1));
            float cn0 = sf0 * c_lds[m_e][j2] + si0 * tg0;
            float cn1 = sf1 * c_lds[m_e][j2 + 1] + si1 * tg1;
            c_lds[m_e][j2] = cn0;
            c_lds[m_e][j2 + 1] = cn1;
            float h0 = so0 * (1.f - 2.f / (__expf(2.f * cn0) + 1.f));
            float h1 = so1 * (1.f - 2.f / (__expf(2.f * cn1) + 1.f));
            unsigned pv = (unsigned)(unsigned short)f2bf(h0)
                        | ((unsigned)(unsigned short)f2bf(h1) << 16);
            unsigned* hp = (unsigned*)(hnxt + (size_t)(m0 + m_e) * HH + j0 + j2);
            __hip_atomic_store(hp, pv, __ATOMIC_RELAXED, __HIP_MEMORY_SCOPE_AGENT);
            if (t == SS - 1) {
                float2 hv = make_float2(h0, h1);
                *(float2*)(hf + (size_t)(m0 + m_e) * HH + j0 + j2) = hv;
            }
        }

        if (t == SS - 1) break;

        // ---- grid barrier, epoch e = t+1; x-part of t+1 hides under it ----
        const unsigned e = (unsigned)(t + 1);
        __syncthreads();   // all lanes' h atomic-stores drained (vmcnt(0) before s_barrier)
        if (!dead && tid == 0)
            __hip_atomic_store(&flags[bid], e, __ATOMIC_RELEASE, __HIP_MEMORY_SCOPE_AGENT);

        // x-part of step t+1 (h-independent) — overlaps flag propagation
        acc0 = f32x4{0.f, 0.f, 0.f, 0.f}; acc1 = acc0;
        {
            const float* xt = xrow + (size_t)(t + 1) * II;
#pragma unroll
            for (int kk = 0; kk < 4; kk++) {
                const float4* xp = (const float4*)(xt + kk * 32 + lq * 8);
                float4 x0 = xp[0], x1 = xp[1];
                short8v a;
                a[0] = f2bf(x0.x); a[1] = f2bf(x0.y); a[2] = f2bf(x0.z); a[3] = f2bf(x0.w);
                a[4] = f2bf(x1.x); a[5] = f2bf(x1.y); a[6] = f2bf(x1.z); a[7] = f2bf(x1.w);
                acc0 = __builtin_amdgcn_mfma_f32_16x16x32_bf16(a, Bw[kk][0], acc0, 0, 0, 0);
                acc1 = __builtin_amdgcn_mfma_f32_16x16x32_bf16(a, Bw[kk][1], acc1, 0, 0, 0);
            }
        }

        // poll ALL 256 arrival flags (relaxed, no per-iteration cache inv)
        if (!dead && tid < 64) {
            for (int f = tid; f < NB; f += 64) {
                int it = 0;
                while (__hip_atomic_load(&flags[f], __ATOMIC_RELAXED,
                                         __HIP_MEMORY_SCOPE_AGENT) < e) {
                    if (++it > SPIN_LIM) { dead = 1; break; }
                }
                if (dead) break;
            }
        }
        __syncthreads();
        // one agent acquire fence per wave per step: orders h-loads of t+1
        __builtin_amdgcn_fence(__ATOMIC_ACQUIRE, "agent");
    }

    (void)dead;
}

// ---------------------------------------------------------------------------
// out[b][o] = h[b] . W_out[o] + b_out[o].  grid 128 (b), block 256.
// ---------------------------------------------------------------------------
__global__ void final_linear(const float* __restrict__ hf, const float* __restrict__ Wout,
                             const float* __restrict__ bout, float* __restrict__ out) {
    __shared__ float hs[HH];
    const int b = blockIdx.x;
    for (int i = threadIdx.x; i < HH; i += 256) hs[i] = hf[(size_t)b * HH + i];
    __syncthreads();
    const int w = threadIdx.x >> 6, l = threadIdx.x & 63;
    for (int o = w; o < NC; o += 4) {
        float s = 0.f;
        const float* wr = Wout + (size_t)o * HH;
        for (int jj = l; jj < HH; jj += 64) s += hs[jj] * wr[jj];
#pragma unroll
        for (int d = 32; d > 0; d >>= 1) s += __shfl_down(s, d);
        if (l == 0) out[b * NC + o] = s + bout[o];
    }
}

extern "C" void kernel_launch(void* const* d_in, const int* in_sizes, int n_in,
                              void* d_out, int out_size, void* d_ws, size_t ws_size,
                              hipStream_t stream) {
    const float* x    = (const float*)d_in[0];
    const float* W_ii = (const float*)d_in[1];
    const float* W_hi = (const float*)d_in[2];
    const float* b_ii = (const float*)d_in[3];
    const float* W_if = (const float*)d_in[4];
    const float* W_hf = (const float*)d_in[5];
    const float* b_if = (const float*)d_in[6];
    const float* W_ig = (const float*)d_in[7];
    const float* W_hg = (const float*)d_in[8];
    const float* b_ig = (const float*)d_in[9];
    const float* W_io = (const float*)d_in[10];
    const float* W_ho = (const float*)d_in[11];
    const float* b_io = (const float*)d_in[12];
    const float* W_out = (const float*)d_in[13];
    const float* b_out = (const float*)d_in[14];

    char* ws = (char*)d_ws;
    short* Bt   = (short*)ws;                                  // 9,437,184 B
    float* b4   = (float*)(ws + 9437184);                      // 16,384 B
    short* hbuf = (short*)(ws + 9437184 + 16384);              // 524,288 B
    float* hf   = (float*)(ws + 9437184 + 16384 + 524288);     // 524,288 B
    unsigned* flags = (unsigned*)(ws + 9437184 + 16384 + 524288 + 524288); // 4,096 B

    prep_weights<<<dim3(36, 32, 4), dim3(32, 8), 0, stream>>>(
        W_ii, W_if, W_ig, W_io, W_hi, W_hf, W_hg, W_ho, Bt);
    prep_misc<<<512, 256, 0, stream>>>(b_ii, b_if, b_ig, b_io, b4, hbuf, flags);

    lstm_persist<<<NB, 256, 0, stream>>>(x, Bt, b4, hbuf, hf, flags);

    final_linear<<<BB, 256, 0, stream>>>(hf, W_out, b_out, (float*)d_out);
}

// Round 5
// 8043.687 us; speedup vs baseline: 5.3389x; 2.4107x over previous
//
#include <hip/hip_runtime.h>
#include <hip/hip_bf16.h>

#define BB 128
#define SS 1000
#define II 128
#define HH 1024
#define G4 4096
#define KK (II + HH)   // 1152
#define NC 50
#define NB 256         // persistent blocks (8 groups x 32)
#define SPIN_LIM (1 << 20)

typedef __attribute__((ext_vector_type(8))) short short8v;
typedef __attribute__((ext_vector_type(4))) float f32x4;

static __device__ __forceinline__ short f2bf(float f) {
    union { float f; unsigned u; } v; v.f = f;
    unsigned u = v.u;
    u += 0x7FFFu + ((u >> 16) & 1u);   // RNE
    return (short)(u >> 16);
}

// ---------------------------------------------------------------------------
// Weight prep: Bt[n][k] (bf16, n = gate*1024 + j, k in [0,1152)) from fp32.
// grid (36, 32, 4), block (32, 8)
// ---------------------------------------------------------------------------
__global__ void prep_weights(const float* __restrict__ Wx0, const float* __restrict__ Wx1,
                             const float* __restrict__ Wx2, const float* __restrict__ Wx3,
                             const float* __restrict__ Wh0, const float* __restrict__ Wh1,
                             const float* __restrict__ Wh2, const float* __restrict__ Wh3,
                             short* __restrict__ Bt) {
    __shared__ float lds[32][33];
    const int kt = blockIdx.x, jt = blockIdx.y, g = blockIdx.z;
    const int tx = threadIdx.x, ty = threadIdx.y;
    const float* Wx = (g == 0) ? Wx0 : (g == 1) ? Wx1 : (g == 2) ? Wx2 : Wx3;
    const float* Wh = (g == 0) ? Wh0 : (g == 1) ? Wh1 : (g == 2) ? Wh2 : Wh3;
    const int k0 = kt * 32, j0 = jt * 32;
#pragma unroll
    for (int r = 0; r < 4; r++) {
        int kk = k0 + ty + r * 8;
        float v = (kk < II) ? Wx[kk * HH + j0 + tx] : Wh[(kk - II) * HH + j0 + tx];
        lds[ty + r * 8][tx] = v;
    }
    __syncthreads();
#pragma unroll
    for (int r = 0; r < 4; r++) {
        int jj = ty + r * 8;
        Bt[(size_t)(g * HH + j0 + jj) * KK + k0 + tx] = f2bf(lds[tx][jj]);
    }
}

// ---------------------------------------------------------------------------
// Pack bias [4096], zero hbuf[0], zero barrier flags. grid 512, block 256.
// ---------------------------------------------------------------------------
__global__ void prep_misc(const float* __restrict__ bi, const float* __restrict__ bf_,
                          const float* __restrict__ bg, const float* __restrict__ bo,
                          float* __restrict__ b4, short* __restrict__ hbuf,
                          unsigned* __restrict__ flags) {
    int i = blockIdx.x * 256 + threadIdx.x;
    if (i < G4) {
        float v = (i < HH) ? bi[i] : (i < 2 * HH) ? bf_[i - HH]
                : (i < 3 * HH) ? bg[i - 2 * HH] : bo[i - 3 * HH];
        b4[i] = v;
    }
    if (i < BB * HH) hbuf[i] = 0;   // h(0) = 0 in buffer 0
    if (i < 1024) flags[i] = 0;     // barrier flags (8 groups x 64 slots)
}

// ---------------------------------------------------------------------------
// Persistent LSTM. 256 blocks x 256 threads, 1 block/CU.
// 8 INDEPENDENT groups: group mg = bid&7 owns batch rows [mg*16, +16) and
// syncs only within itself (32 blocks, its own 128B flag line). With XCD
// round-robin dispatch the whole group is XCD-local (perf only; correctness
// is agent-scope, placement-independent).
// No fences in the loop: h stores = relaxed agent atomic u32 (write-through
// to coherence point); h reads = relaxed agent atomic 8B (bypass stale L1/L2)
// staged once per block into LDS; flag store relaxed after __syncthreads
// (vmcnt drained -> h-stores acked before flag issues).
// ---------------------------------------------------------------------------
__global__ __launch_bounds__(256, 1) void lstm_persist(
    const float* __restrict__ x, const short* __restrict__ Bt,
    const float* __restrict__ b4, short* __restrict__ hbuf,
    float* __restrict__ hf, unsigned* __restrict__ flags) {
    const int bid = blockIdx.x;
    const int mg = bid & 7, jg = bid >> 3;
    const int m0 = mg * 16, j0 = jg * 32;
    const int tid = threadIdx.x;
    const int g = tid >> 6, l = tid & 63;
    const int lq = l >> 4, lr = l & 15;
    unsigned* gflags = flags + mg * 64;      // this group's flag line

    __shared__ __align__(16) short hstage[16 * 1032];   // row stride 2064 B
    __shared__ float g4s[4][16][33];
    __shared__ float c_lds[16][33];
    __shared__ int dead;

    if (tid == 0) dead = 0;
    for (int i = tid; i < 16 * 33; i += 256) ((float*)c_lds)[i] = 0.f;

    // --- this wave's weight slice -> registers/AGPRs (once) ---
    short8v Bw[36][2];
    {
        const short* Bg = Bt + (size_t)(g * HH + j0) * KK;
#pragma unroll
        for (int kk = 0; kk < 36; kk++) {
#pragma unroll
            for (int nt = 0; nt < 2; nt++) {
                Bw[kk][nt] = *(const short8v*)(Bg + (size_t)(nt * 16 + lr) * KK + kk * 32 + lq * 8);
            }
        }
    }

    const int arow = m0 + lr;                       // A-operand batch row
    const float* xrow = x + (size_t)arow * SS * II;

    // elementwise constants: thread -> (m_e, cols j2, j2+1)
    const int m_e = tid >> 4;            // 0..15
    const int j2 = (tid & 15) * 2;       // 0..30
    const float bi0 = b4[j0 + j2],          bi1 = b4[j0 + j2 + 1];
    const float bf0 = b4[HH + j0 + j2],     bf1 = b4[HH + j0 + j2 + 1];
    const float bg0 = b4[2 * HH + j0 + j2], bg1 = b4[2 * HH + j0 + j2 + 1];
    const float bo0 = b4[3 * HH + j0 + j2], bo1 = b4[3 * HH + j0 + j2 + 1];

    __syncthreads();

    f32x4 acc0 = {0.f, 0.f, 0.f, 0.f}, acc1 = acc0;

    // prologue: x-part of step 0
#pragma unroll
    for (int kk = 0; kk < 4; kk++) {
        const float4* xp = (const float4*)(xrow + kk * 32 + lq * 8);
        float4 x0 = xp[0], x1 = xp[1];
        short8v a;
        a[0] = f2bf(x0.x); a[1] = f2bf(x0.y); a[2] = f2bf(x0.z); a[3] = f2bf(x0.w);
        a[4] = f2bf(x1.x); a[5] = f2bf(x1.y); a[6] = f2bf(x1.z); a[7] = f2bf(x1.w);
        acc0 = __builtin_amdgcn_mfma_f32_16x16x32_bf16(a, Bw[kk][0], acc0, 0, 0, 0);
        acc1 = __builtin_amdgcn_mfma_f32_16x16x32_bf16(a, Bw[kk][1], acc1, 0, 0, 0);
    }

    for (int t = 0; t < SS; t++) {
        const short* hcur = hbuf + (size_t)(t & 1) * (BB * HH);
        short* hnxt = hbuf + (size_t)((t + 1) & 1) * (BB * HH);

        // 1. wait for h(t): poll this group's 32 flags (lane i -> flag i)
        if (!dead && tid < 32) {
            const unsigned e = (unsigned)t;
            int it = 0;
            while (__hip_atomic_load(&gflags[tid], __ATOMIC_RELAXED,
                                     __HIP_MEMORY_SCOPE_AGENT) < e) {
                if (++it > SPIN_LIM) { dead = 1; break; }
            }
        }
        __syncthreads();

        // 2. stage h(t) [16 x 1024 bf16 = 32KB] -> LDS (coherent 8B loads)
        {
            const unsigned long long* hsrc =
                (const unsigned long long*)(hcur + (size_t)m0 * HH);
#pragma unroll
            for (int it = 0; it < 16; it++) {
                int wx = tid + it * 256;            // 0..4095
                int row = wx >> 8, c8 = wx & 255;   // 256 x 8B per row
                unsigned long long v = __hip_atomic_load(
                    hsrc + (size_t)row * 256 + c8,
                    __ATOMIC_RELAXED, __HIP_MEMORY_SCOPE_AGENT);
                *(unsigned long long*)((char*)hstage + row * 2064 + c8 * 8) = v;
            }
        }
        __syncthreads();

        // 3. h-part MFMAs: A-fragments from LDS (2-way-free bank pattern)
#pragma unroll
        for (int kk2 = 0; kk2 < 32; kk2++) {
            short8v a = *(const short8v*)((const char*)hstage + lr * 2064 + kk2 * 64 + lq * 16);
            acc0 = __builtin_amdgcn_mfma_f32_16x16x32_bf16(a, Bw[kk2 + 4][0], acc0, 0, 0, 0);
            acc1 = __builtin_amdgcn_mfma_f32_16x16x32_bf16(a, Bw[kk2 + 4][1], acc1, 0, 0, 0);
        }

        // 4. gates -> LDS   (C/D map: col = lane&15, row = lq*4 + r)
#pragma unroll
        for (int r = 0; r < 4; r++) {
            g4s[g][lq * 4 + r][lr] = acc0[r];
            g4s[g][lq * 4 + r][16 + lr] = acc1[r];
        }
        __syncthreads();

        // elementwise: 1 thread -> (m_e, j2) and (m_e, j2+1)
        {
            float gi0 = g4s[0][m_e][j2] + bi0, gi1 = g4s[0][m_e][j2 + 1] + bi1;
            float gf0 = g4s[1][m_e][j2] + bf0, gf1 = g4s[1][m_e][j2 + 1] + bf1;
            float gg0 = g4s[2][m_e][j2] + bg0, gg1 = g4s[2][m_e][j2 + 1] + bg1;
            float go0 = g4s[3][m_e][j2] + bo0, go1 = g4s[3][m_e][j2 + 1] + bo1;
            float si0 = 1.f / (1.f + __expf(-gi0)), si1 = 1.f / (1.f + __expf(-gi1));
            float sf0 = 1.f / (1.f + __expf(-gf0)), sf1 = 1.f / (1.f + __expf(-gf1));
            float tg0 = 1.f - 2.f / (__expf(2.f * gg0) + 1.f);
            float tg1 = 1.f - 2.f / (__expf(2.f * gg1) + 1.f);
            float so0 = 1.f / (1.f + __expf(-go0)), so1 = 1.f / (1.f + __expf(-go1));
            float cn0 = sf0 * c_lds[m_e][j2] + si0 * tg0;
            float cn1 = sf1 * c_lds[m_e][j2 + 1] + si1 * tg1;
            c_lds[m_e][j2] = cn0;
            c_lds[m_e][j2 + 1] = cn1;
            float h0 = so0 * (1.f - 2.f / (__expf(2.f * cn0) + 1.f));
            float h1 = so1 * (1.f - 2.f / (__expf(2.f * cn1) + 1.f));
            unsigned pv = (unsigned)(unsigned short)f2bf(h0)
                        | ((unsigned)(unsigned short)f2bf(h1) << 16);
            unsigned* hp = (unsigned*)(hnxt + (size_t)(m0 + m_e) * HH + j0 + j2);
            __hip_atomic_store(hp, pv, __ATOMIC_RELAXED, __HIP_MEMORY_SCOPE_AGENT);
            if (t == SS - 1) {
                float2 hv = make_float2(h0, h1);
                *(float2*)(hf + (size_t)(m0 + m_e) * HH + j0 + j2) = hv;
            }
        }

        if (t == SS - 1) break;

        // 5. publish h(t+1): syncthreads drains all waves' vmcnt (stores
        // acked at coherence point), then relaxed flag store.
        __syncthreads();
        if (!dead && tid == 0)
            __hip_atomic_store(&gflags[jg], (unsigned)(t + 1),
                               __ATOMIC_RELAXED, __HIP_MEMORY_SCOPE_AGENT);

        // 6. x-part of step t+1 (h-independent) — overlaps flag propagation
        acc0 = f32x4{0.f, 0.f, 0.f, 0.f}; acc1 = acc0;
        {
            const float* xt = xrow + (size_t)(t + 1) * II;
#pragma unroll
            for (int kk = 0; kk < 4; kk++) {
                const float4* xp = (const float4*)(xt + kk * 32 + lq * 8);
                float4 x0 = xp[0], x1 = xp[1];
                short8v a;
                a[0] = f2bf(x0.x); a[1] = f2bf(x0.y); a[2] = f2bf(x0.z); a[3] = f2bf(x0.w);
                a[4] = f2bf(x1.x); a[5] = f2bf(x1.y); a[6] = f2bf(x1.z); a[7] = f2bf(x1.w);
                acc0 = __builtin_amdgcn_mfma_f32_16x16x32_bf16(a, Bw[kk][0], acc0, 0, 0, 0);
                acc1 = __builtin_amdgcn_mfma_f32_16x16x32_bf16(a, Bw[kk][1], acc1, 0, 0, 0);
            }
        }
    }

    (void)dead;
}

// ---------------------------------------------------------------------------
// out[b][o] = h[b] . W_out[o] + b_out[o].  grid 128 (b), block 256.
// ---------------------------------------------------------------------------
__global__ void final_linear(const float* __restrict__ hf, const float* __restrict__ Wout,
                             const float* __restrict__ bout, float* __restrict__ out) {
    __shared__ float hs[HH];
    const int b = blockIdx.x;
    for (int i = threadIdx.x; i < HH; i += 256) hs[i] = hf[(size_t)b * HH + i];
    __syncthreads();
    const int w = threadIdx.x >> 6, l = threadIdx.x & 63;
    for (int o = w; o < NC; o += 4) {
        float s = 0.f;
        const float* wr = Wout + (size_t)o * HH;
        for (int jj = l; jj < HH; jj += 64) s += hs[jj] * wr[jj];
#pragma unroll
        for (int d = 32; d > 0; d >>= 1) s += __shfl_down(s, d);
        if (l == 0) out[b * NC + o] = s + bout[o];
    }
}

extern "C" void kernel_launch(void* const* d_in, const int* in_sizes, int n_in,
                              void* d_out, int out_size, void* d_ws, size_t ws_size,
                              hipStream_t stream) {
    const float* x    = (const float*)d_in[0];
    const float* W_ii = (const float*)d_in[1];
    const float* W_hi = (const float*)d_in[2];
    const float* b_ii = (const float*)d_in[3];
    const float* W_if = (const float*)d_in[4];
    const float* W_hf = (const float*)d_in[5];
    const float* b_if = (const float*)d_in[6];
    const float* W_ig = (const float*)d_in[7];
    const float* W_hg = (const float*)d_in[8];
    const float* b_ig = (const float*)d_in[9];
    const float* W_io = (const float*)d_in[10];
    const float* W_ho = (const float*)d_in[11];
    const float* b_io = (const float*)d_in[12];
    const float* W_out = (const float*)d_in[13];
    const float* b_out = (const float*)d_in[14];

    char* ws = (char*)d_ws;
    short* Bt   = (short*)ws;                                  // 9,437,184 B
    float* b4   = (float*)(ws + 9437184);                      // 16,384 B
    short* hbuf = (short*)(ws + 9437184 + 16384);              // 524,288 B
    float* hf   = (float*)(ws + 9437184 + 16384 + 524288);     // 524,288 B
    unsigned* flags = (unsigned*)(ws + 9437184 + 16384 + 524288 + 524288); // 4,096 B

    prep_weights<<<dim3(36, 32, 4), dim3(32, 8), 0, stream>>>(
        W_ii, W_if, W_ig, W_io, W_hi, W_hf, W_hg, W_ho, Bt);
    prep_misc<<<512, 256, 0, stream>>>(b_ii, b_if, b_ig, b_io, b4, hbuf, flags);

    lstm_persist<<<NB, 256, 0, stream>>>(x, Bt, b4, hbuf, hf, flags);

    final_linear<<<BB, 256, 0, stream>>>(hf, W_out, b_out, (float*)d_out);
}

// Round 6
// 4700.538 us; speedup vs baseline: 9.1361x; 1.7112x over previous
//
#include <hip/hip_runtime.h>
#include <hip/hip_bf16.h>

#define BB 128
#define SS 1000
#define II 128
#define HH 1024
#define G4 4096
#define KK (II + HH)   // 1152
#define NC 50
#define NB 256         // persistent blocks (8 groups x 32)
#define SPIN_LIM (1 << 20)

typedef __attribute__((ext_vector_type(8))) short short8v;
typedef __attribute__((ext_vector_type(4))) float f32x4;

static __device__ __forceinline__ short f2bf(float f) {
    union { float f; unsigned u; } v; v.f = f;
    unsigned u = v.u;
    u += 0x7FFFu + ((u >> 16) & 1u);   // RNE
    return (short)(u >> 16);
}

// ---------------------------------------------------------------------------
// Weight prep: Bt[n][k] (bf16, n = gate*1024 + j, k in [0,1152)) from fp32.
// grid (36, 32, 4), block (32, 8)
// ---------------------------------------------------------------------------
__global__ void prep_weights(const float* __restrict__ Wx0, const float* __restrict__ Wx1,
                             const float* __restrict__ Wx2, const float* __restrict__ Wx3,
                             const float* __restrict__ Wh0, const float* __restrict__ Wh1,
                             const float* __restrict__ Wh2, const float* __restrict__ Wh3,
                             short* __restrict__ Bt) {
    __shared__ float lds[32][33];
    const int kt = blockIdx.x, jt = blockIdx.y, g = blockIdx.z;
    const int tx = threadIdx.x, ty = threadIdx.y;
    const float* Wx = (g == 0) ? Wx0 : (g == 1) ? Wx1 : (g == 2) ? Wx2 : Wx3;
    const float* Wh = (g == 0) ? Wh0 : (g == 1) ? Wh1 : (g == 2) ? Wh2 : Wh3;
    const int k0 = kt * 32, j0 = jt * 32;
#pragma unroll
    for (int r = 0; r < 4; r++) {
        int kk = k0 + ty + r * 8;
        float v = (kk < II) ? Wx[kk * HH + j0 + tx] : Wh[(kk - II) * HH + j0 + tx];
        lds[ty + r * 8][tx] = v;
    }
    __syncthreads();
#pragma unroll
    for (int r = 0; r < 4; r++) {
        int jj = ty + r * 8;
        Bt[(size_t)(g * HH + j0 + jj) * KK + k0 + tx] = f2bf(lds[tx][jj]);
    }
}

// ---------------------------------------------------------------------------
// Pack bias [4096], zero hbuf[0], zero barrier flags. grid 512, block 256.
// ---------------------------------------------------------------------------
__global__ void prep_misc(const float* __restrict__ bi, const float* __restrict__ bf_,
                          const float* __restrict__ bg, const float* __restrict__ bo,
                          float* __restrict__ b4, short* __restrict__ hbuf,
                          unsigned* __restrict__ flags) {
    int i = blockIdx.x * 256 + threadIdx.x;
    if (i < G4) {
        float v = (i < HH) ? bi[i] : (i < 2 * HH) ? bf_[i - HH]
                : (i < 3 * HH) ? bg[i - 2 * HH] : bo[i - 3 * HH];
        b4[i] = v;
    }
    if (i < BB * HH) hbuf[i] = 0;   // h(0) = 0 in buffer 0
    if (i < 1024) flags[i] = 0;     // barrier flags (8 groups x 64 slots)
}

// ---------------------------------------------------------------------------
// Persistent LSTM. 256 blocks x 256 threads, 1 block/CU.
// 8 independent groups (mg = bid&7, 16 batch rows each), group-local flag
// barrier, no cache-maintenance ops in the loop. h stores = relaxed agent
// atomic u32 (write-through); h reads = relaxed agent atomic 8B, BATCHED into
// 16 registers (single latency exposure), then written to LDS with the
// (row&7)<<4 XOR swizzle (T2) -> conflict-free ds_read_b128 fragments.
// ---------------------------------------------------------------------------
__global__ __launch_bounds__(256, 1) void lstm_persist(
    const float* __restrict__ x, const short* __restrict__ Bt,
    const float* __restrict__ b4, short* __restrict__ hbuf,
    float* __restrict__ hf, unsigned* __restrict__ flags) {
    const int bid = blockIdx.x;
    const int mg = bid & 7, jg = bid >> 3;
    const int m0 = mg * 16, j0 = jg * 32;
    const int tid = threadIdx.x;
    const int g = tid >> 6, l = tid & 63;
    const int lq = l >> 4, lr = l & 15;
    unsigned* gflags = flags + mg * 64;      // this group's flag line

    __shared__ __align__(16) short hstage[16 * 1024];   // linear 2048B rows, XOR-swizzled content
    __shared__ float g4s[4][16][33];
    __shared__ float c_lds[16][33];
    __shared__ int dead;

    if (tid == 0) dead = 0;
    for (int i = tid; i < 16 * 33; i += 256) ((float*)c_lds)[i] = 0.f;

    // --- this wave's weight slice -> registers (once) ---
    short8v Bw[36][2];
    {
        const short* Bg = Bt + (size_t)(g * HH + j0) * KK;
#pragma unroll
        for (int kk = 0; kk < 36; kk++) {
#pragma unroll
            for (int nt = 0; nt < 2; nt++) {
                Bw[kk][nt] = *(const short8v*)(Bg + (size_t)(nt * 16 + lr) * KK + kk * 32 + lq * 8);
            }
        }
    }

    const int arow = m0 + lr;                       // A-operand batch row
    const float* xrow = x + (size_t)arow * SS * II;

    // elementwise constants: thread -> (m_e, cols j2, j2+1)
    const int m_e = tid >> 4;            // 0..15
    const int j2 = (tid & 15) * 2;       // 0..30
    const float bi0 = b4[j0 + j2],          bi1 = b4[j0 + j2 + 1];
    const float bf0 = b4[HH + j0 + j2],     bf1 = b4[HH + j0 + j2 + 1];
    const float bg0 = b4[2 * HH + j0 + j2], bg1 = b4[2 * HH + j0 + j2 + 1];
    const float bo0 = b4[3 * HH + j0 + j2], bo1 = b4[3 * HH + j0 + j2 + 1];

    __syncthreads();

    f32x4 acc0 = {0.f, 0.f, 0.f, 0.f}, acc1 = acc0;

    // prologue: x-part of step 0
#pragma unroll
    for (int kk = 0; kk < 4; kk++) {
        const float4* xp = (const float4*)(xrow + kk * 32 + lq * 8);
        float4 x0 = xp[0], x1 = xp[1];
        short8v a;
        a[0] = f2bf(x0.x); a[1] = f2bf(x0.y); a[2] = f2bf(x0.z); a[3] = f2bf(x0.w);
        a[4] = f2bf(x1.x); a[5] = f2bf(x1.y); a[6] = f2bf(x1.z); a[7] = f2bf(x1.w);
        acc0 = __builtin_amdgcn_mfma_f32_16x16x32_bf16(a, Bw[kk][0], acc0, 0, 0, 0);
        acc1 = __builtin_amdgcn_mfma_f32_16x16x32_bf16(a, Bw[kk][1], acc1, 0, 0, 0);
    }

    for (int t = 0; t < SS; t++) {
        const short* hcur = hbuf + (size_t)(t & 1) * (BB * HH);
        short* hnxt = hbuf + (size_t)((t + 1) & 1) * (BB * HH);

        // 1. wait for h(t): poll this group's 32 flags (lane i -> flag i)
        if (!dead && tid < 32) {
            const unsigned e = (unsigned)t;
            int it = 0;
            while (__hip_atomic_load(&gflags[tid], __ATOMIC_RELAXED,
                                     __HIP_MEMORY_SCOPE_AGENT) < e) {
                if (++it > SPIN_LIM) { dead = 1; break; }
            }
        }
        __syncthreads();

        // 2. stage h(t) [16 rows x 2KB] -> LDS. Batch ALL 16 coherent loads
        //    into registers (pipelined, one latency exposure), then LDS-write
        //    with XOR swizzle (bits 4-6 ^= row&7).
        {
            const unsigned long long* hsrc =
                (const unsigned long long*)(hcur + (size_t)m0 * HH);
            unsigned long long v[16];
#pragma unroll
            for (int it = 0; it < 16; it++)
                v[it] = __hip_atomic_load(hsrc + it * 256 + tid,
                                          __ATOMIC_RELAXED, __HIP_MEMORY_SCOPE_AGENT);
#pragma unroll
            for (int it = 0; it < 16; it++) {
                int off = (tid * 8) ^ ((it & 7) << 4);
                *(unsigned long long*)((char*)hstage + it * 2048 + off) = v[it];
            }
        }
        __syncthreads();

        // 3. h-part MFMAs: A-fragments from LDS (swizzled read, 2-way max)
#pragma unroll
        for (int kk2 = 0; kk2 < 32; kk2++) {
            short8v a = *(const short8v*)((const char*)hstage + lr * 2048 +
                                          ((kk2 * 64 + lq * 16) ^ ((lr & 7) << 4)));
            acc0 = __builtin_amdgcn_mfma_f32_16x16x32_bf16(a, Bw[kk2 + 4][0], acc0, 0, 0, 0);
            acc1 = __builtin_amdgcn_mfma_f32_16x16x32_bf16(a, Bw[kk2 + 4][1], acc1, 0, 0, 0);
        }

        // 4. gates -> LDS   (C/D map: col = lane&15, row = lq*4 + r)
#pragma unroll
        for (int r = 0; r < 4; r++) {
            g4s[g][lq * 4 + r][lr] = acc0[r];
            g4s[g][lq * 4 + r][16 + lr] = acc1[r];
        }
        __syncthreads();

        // elementwise: 1 thread -> (m_e, j2) and (m_e, j2+1)
        {
            float gi0 = g4s[0][m_e][j2] + bi0, gi1 = g4s[0][m_e][j2 + 1] + bi1;
            float gf0 = g4s[1][m_e][j2] + bf0, gf1 = g4s[1][m_e][j2 + 1] + bf1;
            float gg0 = g4s[2][m_e][j2] + bg0, gg1 = g4s[2][m_e][j2 + 1] + bg1;
            float go0 = g4s[3][m_e][j2] + bo0, go1 = g4s[3][m_e][j2 + 1] + bo1;
            float si0 = 1.f / (1.f + __expf(-gi0)), si1 = 1.f / (1.f + __expf(-gi1));
            float sf0 = 1.f / (1.f + __expf(-gf0)), sf1 = 1.f / (1.f + __expf(-gf1));
            float tg0 = 1.f - 2.f / (__expf(2.f * gg0) + 1.f);
            float tg1 = 1.f - 2.f / (__expf(2.f * gg1) + 1.f);
            float so0 = 1.f / (1.f + __expf(-go0)), so1 = 1.f / (1.f + __expf(-go1));
            float cn0 = sf0 * c_lds[m_e][j2] + si0 * tg0;
            float cn1 = sf1 * c_lds[m_e][j2 + 1] + si1 * tg1;
            c_lds[m_e][j2] = cn0;
            c_lds[m_e][j2 + 1] = cn1;
            float h0 = so0 * (1.f - 2.f / (__expf(2.f * cn0) + 1.f));
            float h1 = so1 * (1.f - 2.f / (__expf(2.f * cn1) + 1.f));
            unsigned pv = (unsigned)(unsigned short)f2bf(h0)
                        | ((unsigned)(unsigned short)f2bf(h1) << 16);
            unsigned* hp = (unsigned*)(hnxt + (size_t)(m0 + m_e) * HH + j0 + j2);
            __hip_atomic_store(hp, pv, __ATOMIC_RELAXED, __HIP_MEMORY_SCOPE_AGENT);
            if (t == SS - 1) {
                float2 hv = make_float2(h0, h1);
                *(float2*)(hf + (size_t)(m0 + m_e) * HH + j0 + j2) = hv;
            }
        }

        if (t == SS - 1) break;

        // 5. publish h(t+1): syncthreads drains all waves' vmcnt (stores
        // acked at coherence point), then relaxed flag store.
        __syncthreads();
        if (!dead && tid == 0)
            __hip_atomic_store(&gflags[jg], (unsigned)(t + 1),
                               __ATOMIC_RELAXED, __HIP_MEMORY_SCOPE_AGENT);

        // 6. x-part of step t+1 (h-independent) — overlaps flag propagation
        acc0 = f32x4{0.f, 0.f, 0.f, 0.f}; acc1 = acc0;
        {
            const float* xt = xrow + (size_t)(t + 1) * II;
#pragma unroll
            for (int kk = 0; kk < 4; kk++) {
                const float4* xp = (const float4*)(xt + kk * 32 + lq * 8);
                float4 x0 = xp[0], x1 = xp[1];
                short8v a;
                a[0] = f2bf(x0.x); a[1] = f2bf(x0.y); a[2] = f2bf(x0.z); a[3] = f2bf(x0.w);
                a[4] = f2bf(x1.x); a[5] = f2bf(x1.y); a[6] = f2bf(x1.z); a[7] = f2bf(x1.w);
                acc0 = __builtin_amdgcn_mfma_f32_16x16x32_bf16(a, Bw[kk][0], acc0, 0, 0, 0);
                acc1 = __builtin_amdgcn_mfma_f32_16x16x32_bf16(a, Bw[kk][1], acc1, 0, 0, 0);
            }
        }
    }

    (void)dead;
}

// ---------------------------------------------------------------------------
// out[b][o] = h[b] . W_out[o] + b_out[o].  grid 128 (b), block 256.
// ---------------------------------------------------------------------------
__global__ void final_linear(const float* __restrict__ hf, const float* __restrict__ Wout,
                             const float* __restrict__ bout, float* __restrict__ out) {
    __shared__ float hs[HH];
    const int b = blockIdx.x;
    for (int i = threadIdx.x; i < HH; i += 256) hs[i] = hf[(size_t)b * HH + i];
    __syncthreads();
    const int w = threadIdx.x >> 6, l = threadIdx.x & 63;
    for (int o = w; o < NC; o += 4) {
        float s = 0.f;
        const float* wr = Wout + (size_t)o * HH;
        for (int jj = l; jj < HH; jj += 64) s += hs[jj] * wr[jj];
#pragma unroll
        for (int d = 32; d > 0; d >>= 1) s += __shfl_down(s, d);
        if (l == 0) out[b * NC + o] = s + bout[o];
    }
}

extern "C" void kernel_launch(void* const* d_in, const int* in_sizes, int n_in,
                              void* d_out, int out_size, void* d_ws, size_t ws_size,
                              hipStream_t stream) {
    const float* x    = (const float*)d_in[0];
    const float* W_ii = (const float*)d_in[1];
    const float* W_hi = (const float*)d_in[2];
    const float* b_ii = (const float*)d_in[3];
    const float* W_if = (const float*)d_in[4];
    const float* W_hf = (const float*)d_in[5];
    const float* b_if = (const float*)d_in[6];
    const float* W_ig = (const float*)d_in[7];
    const float* W_hg = (const float*)d_in[8];
    const float* b_ig = (const float*)d_in[9];
    const float* W_io = (const float*)d_in[10];
    const float* W_ho = (const float*)d_in[11];
    const float* b_io = (const float*)d_in[12];
    const float* W_out = (const float*)d_in[13];
    const float* b_out = (const float*)d_in[14];

    char* ws = (char*)d_ws;
    short* Bt   = (short*)ws;                                  // 9,437,184 B
    float* b4   = (float*)(ws + 9437184);                      // 16,384 B
    short* hbuf = (short*)(ws + 9437184 + 16384);              // 524,288 B
    float* hf   = (float*)(ws + 9437184 + 16384 + 524288);     // 524,288 B
    unsigned* flags = (unsigned*)(ws + 9437184 + 16384 + 524288 + 524288); // 4,096 B

    prep_weights<<<dim3(36, 32, 4), dim3(32, 8), 0, stream>>>(
        W_ii, W_if, W_ig, W_io, W_hi, W_hf, W_hg, W_ho, Bt);
    prep_misc<<<512, 256, 0, stream>>>(b_ii, b_if, b_ig, b_io, b4, hbuf, flags);

    lstm_persist<<<NB, 256, 0, stream>>>(x, Bt, b4, hbuf, hf, flags);

    final_linear<<<BB, 256, 0, stream>>>(hf, W_out, b_out, (float*)d_out);
}